// Round 1
// baseline (56.742 us; speedup 1.0000x reference)
//
#include <hip/hip_runtime.h>

typedef _Float16 f16;
typedef __attribute__((ext_vector_type(8))) _Float16 f16x8;
typedef __attribute__((ext_vector_type(4))) _Float16 f16x4;
typedef __attribute__((ext_vector_type(4))) float f32x4;

namespace {
constexpr int kL   = 65536;  // sequence length
constexpr int kR   = 256;    // random features
constexpr int kD   = 64;     // feature dim
constexpr int kDV  = 64;     // value dim
constexpr int kCL  = 64;     // chunk of columns per iteration
constexpr int kNCH = 4;      // chunks per block (256 cols/block, 256 blocks)

constexpr float kA   = 0.1f;
constexpr float kB   = 0.7745966692414834f;      // sqrt(0.6)
constexpr float kDnS = 0.2888816545234944f;      // 0.6^16 * 1024 (PHI_SCALE folded in)
constexpr float kOutScale = 9.5367431640625e-7f; // 2^-20 undoes PHI_SCALE^2
}

// ---------------------------------------------------------------------------
// Kernel A: partial KV = phi(K)*2^10 @ V, per-block partial written to scratch
// (we reuse d_out: 256 blocks * 256r * 64dv f32 == out_size exactly)
// ---------------------------------------------------------------------------
__global__ __launch_bounds__(512)
void favor_kv_kernel(const float* __restrict__ Kg, const float* __restrict__ Vg,
                     const float* __restrict__ Wg, float* __restrict__ partials)
{
    __shared__ f16 sKt[64 * 64];    // [l][d], fp16, XOR-swizzled
    __shared__ f16 sVt[64 * 64];    // [dv][l], fp16, XOR-swizzled
    __shared__ f16 sPhi[256 * 64];  // [r][l], fp16, XOR-swizzled
    __shared__ float sPsq[8 * 64];  // per-group partial column norms

    const int tid  = threadIdx.x;
    const int w    = tid >> 6;
    const int lane = tid & 63;
    const int l15  = lane & 15;
    const int lhi  = lane >> 4;
    const int blk  = blockIdx.x;
    const int lblk = blk * (kCL * kNCH);

    // Register-resident W fragments for this wave's 32-row r tile.
    // A-frag (16x16x32): row = lane&15, k = 8*(lane>>4)+j (+32*ks)
    f16x8 wfrag[2][2];
#pragma unroll
    for (int ri = 0; ri < 2; ++ri)
#pragma unroll
        for (int ks = 0; ks < 2; ++ks) {
            const float* p = Wg + (32 * w + 16 * ri + l15) * kD + 32 * ks + 8 * lhi;
            f16x8 v;
#pragma unroll
            for (int j = 0; j < 8; ++j) v[j] = (f16)p[j];
            wfrag[ri][ks] = v;
        }

    f32x4 acc[4][2];
#pragma unroll
    for (int a = 0; a < 4; ++a)
#pragma unroll
        for (int d = 0; d < 2; ++d) { f32x4 z0 = {0.f, 0.f, 0.f, 0.f}; acc[a][d] = z0; }

    const int wr = w >> 1;          // stage-2: r group (64 rows)
    const int wc = w & 1;           // stage-2: dv half (32 cols)
    const int scol  = tid & 63;     // staging column handled by this thread
    const int dbase = (tid >> 6) * 8;

    for (int t = 0; t < kNCH; ++t) {
        const int l0 = lblk + t * kCL;

        // ---- stage K chunk transposed ([l][d]) + V chunk transposed ([dv][l])
        {
            float kvv[8];
            float s = 0.f;
#pragma unroll
            for (int j = 0; j < 8; ++j) {
                kvv[j] = Kg[(dbase + j) * kL + l0 + scol];
                s += kvv[j] * kvv[j];
            }
            sPsq[(tid >> 6) * 64 + scol] = s;
            f16x8 hk;
#pragma unroll
            for (int j = 0; j < 8; ++j) hk[j] = (f16)kvv[j];
            *(f16x8*)&sKt[scol * 64 + (dbase ^ ((scol & 7) << 3))] = hk;

            f16x8 hv;
#pragma unroll
            for (int j = 0; j < 8; ++j) hv[j] = (f16)Vg[(l0 + dbase + j) * kDV + scol];
            *(f16x8*)&sVt[scol * 64 + (dbase ^ ((scol & 7) << 3))] = hv;
        }
        __syncthreads();

        // per-lane column norm (all waves redundantly; no extra barrier needed)
        float sqv = 0.f;
#pragma unroll
        for (int g = 0; g < 8; ++g) sqv += sPsq[g * 64 + lane];
        float sqs[4];
#pragma unroll
        for (int lf = 0; lf < 4; ++lf) sqs[lf] = __shfl(sqv, lf * 16 + l15, 64);

        // ---- stage 1: Z = W @ K_chunk (this wave: rows 32w..32w+31, all 64 l)
        f32x4 z[2][4];
#pragma unroll
        for (int ri = 0; ri < 2; ++ri)
#pragma unroll
            for (int lf = 0; lf < 4; ++lf) { f32x4 z0 = {0.f, 0.f, 0.f, 0.f}; z[ri][lf] = z0; }

#pragma unroll
        for (int ks = 0; ks < 2; ++ks) {
            f16x8 bfr[4];
#pragma unroll
            for (int lf = 0; lf < 4; ++lf) {
                const int row = 16 * lf + l15;
                bfr[lf] = *(const f16x8*)&sKt[row * 64 + ((32 * ks + 8 * lhi) ^ ((row & 7) << 3))];
            }
#pragma unroll
            for (int ri = 0; ri < 2; ++ri)
#pragma unroll
                for (int lf = 0; lf < 4; ++lf)
                    z[ri][lf] = __builtin_amdgcn_mfma_f32_16x16x32_f16(wfrag[ri][ks], bfr[lf], z[ri][lf], 0, 0, 0);
        }

        // ---- phi = DnS * exp(A + B*z - ||k||^2), write to sPhi [r][l]
#pragma unroll
        for (int ri = 0; ri < 2; ++ri) {
            const int rb = 32 * w + 16 * ri + 4 * lhi;
#pragma unroll
            for (int lf = 0; lf < 4; ++lf) {
                const int lc = 16 * lf + l15;
#pragma unroll
                for (int j = 0; j < 4; ++j) {
                    const float ph = kDnS * __expf(kA + kB * z[ri][lf][j] - sqs[lf]);
                    const int r = rb + j;
                    sPhi[r * 64 + (lc ^ ((r & 7) << 3))] = (f16)ph;
                }
            }
        }
        __syncthreads();

        // ---- stage 2: acc += phi @ V  (wave: rows 64*wr.., cols 32*wc..)
#pragma unroll
        for (int ks = 0; ks < 2; ++ks) {
            f16x8 af[4];
            f16x8 bf[2];
#pragma unroll
            for (int ai = 0; ai < 4; ++ai) {
                const int r = 64 * wr + 16 * ai + l15;
                af[ai] = *(const f16x8*)&sPhi[r * 64 + ((32 * ks + 8 * lhi) ^ ((r & 7) << 3))];
            }
#pragma unroll
            for (int di = 0; di < 2; ++di) {
                const int dv = 32 * wc + 16 * di + l15;
                bf[di] = *(const f16x8*)&sVt[dv * 64 + ((32 * ks + 8 * lhi) ^ ((dv & 7) << 3))];
            }
#pragma unroll
            for (int ai = 0; ai < 4; ++ai)
#pragma unroll
                for (int di = 0; di < 2; ++di)
                    acc[ai][di] = __builtin_amdgcn_mfma_f32_16x16x32_f16(af[ai], bf[di], acc[ai][di], 0, 0, 0);
        }
        __syncthreads();
    }

    // write per-block partial KV
    float* po = partials + blk * (kR * kDV);
#pragma unroll
    for (int ai = 0; ai < 4; ++ai)
#pragma unroll
        for (int di = 0; di < 2; ++di) {
            const int dv = 32 * wc + 16 * di + l15;
#pragma unroll
            for (int j = 0; j < 4; ++j) {
                const int r = 64 * wr + 16 * ai + 4 * lhi + j;
                po[r * kDV + dv] = acc[ai][di][j];
            }
        }
}

// ---------------------------------------------------------------------------
// Kernel R: reduce 256 partial slices -> kv, store fp16 transposed [dv][r]
// ---------------------------------------------------------------------------
__global__ __launch_bounds__(256)
void favor_reduce_kernel(const float* __restrict__ partials, f16* __restrict__ kvt)
{
    __shared__ float red[4 * 64];
    const int t = threadIdx.x;
    const int o = blockIdx.x * 64 + (t & 63);  // output index r*64+dv
    const int g = t >> 6;
    const float* p = partials + (g * 64) * (kR * kDV) + o;
    float s = 0.f;
#pragma unroll
    for (int b = 0; b < 64; ++b) s += p[b * (kR * kDV)];
    red[g * 64 + (t & 63)] = s;
    __syncthreads();
    if (t < 64) {
        const float tot = red[t] + red[64 + t] + red[128 + t] + red[192 + t];
        const int oo = blockIdx.x * 64 + t;
        kvt[(oo & 63) * kR + (oo >> 6)] = (f16)tot;  // [dv][r]
    }
}

// ---------------------------------------------------------------------------
// Kernel B: out = (phi(Q)*2^10)^T @ kv, scaled by 2^-20 at the store
// ---------------------------------------------------------------------------
__global__ __launch_bounds__(512)
void favor_out_kernel(const float* __restrict__ Qg, const f16* __restrict__ kvt,
                      float* __restrict__ outg)
{
    __shared__ f16 sQt[64 * 64];     // [l][d] fp16 swizzled
    __shared__ f16 sPhiT[64 * 256];  // [l][r] fp16 swizzled
    __shared__ float sPsq[8 * 64];

    const int tid  = threadIdx.x;
    const int w    = tid >> 6;
    const int lane = tid & 63;
    const int l15  = lane & 15;
    const int lhi  = lane >> 4;
    const int blk  = blockIdx.x;
    const int lblk = blk * (kCL * kNCH);

    f16x8 wfrag[2][2];
#pragma unroll
    for (int ri = 0; ri < 2; ++ri)
#pragma unroll
        for (int ks = 0; ks < 2; ++ks) {
            const float* p = Qg ? (Qg, (const float*)nullptr) : nullptr; // placeholder removed below
            (void)p;
        }

    // (real W load)
    {
        // Wg passed via kvt? no — W comes as 4th input; see launch: we pass Wg explicitly.
    }
    // NOTE: W pointer is passed as a separate argument; see signature below.
    // (This block intentionally left empty; real code in favor_out_kernel2.)
    (void)wfrag; (void)lblk; (void)blk; (void)lhi; (void)l15; (void)lane; (void)w; (void)tid;
    (void)sQt; (void)sPhiT; (void)sPsq; (void)outg; (void)kvt; (void)Qg;
}

// Proper kernel B with W argument.
__global__ __launch_bounds__(512)
void favor_out_kernel2(const float* __restrict__ Qg, const float* __restrict__ Wg,
                       const f16* __restrict__ kvt, float* __restrict__ outg)
{
    __shared__ f16 sQt[64 * 64];
    __shared__ f16 sPhiT[64 * 256];
    __shared__ float sPsq[8 * 64];

    const int tid  = threadIdx.x;
    const int w    = tid >> 6;
    const int lane = tid & 63;
    const int l15  = lane & 15;
    const int lhi  = lane >> 4;
    const int blk  = blockIdx.x;
    const int lblk = blk * (kCL * kNCH);

    f16x8 wfrag[2][2];
#pragma unroll
    for (int ri = 0; ri < 2; ++ri)
#pragma unroll
        for (int ks = 0; ks < 2; ++ks) {
            const float* p = Wg + (32 * w + 16 * ri + l15) * kD + 32 * ks + 8 * lhi;
            f16x8 v;
#pragma unroll
            for (int j = 0; j < 8; ++j) v[j] = (f16)p[j];
            wfrag[ri][ks] = v;
        }

    const int lfo = w >> 1;  // out l-frag (16 rows) 0..3
    const int dvh = w & 1;   // dv half
    const int scol  = tid & 63;
    const int dbase = (tid >> 6) * 8;

    for (int t = 0; t < kNCH; ++t) {
        const int l0 = lblk + t * kCL;

        {
            float qv[8];
            float s = 0.f;
#pragma unroll
            for (int j = 0; j < 8; ++j) {
                qv[j] = Qg[(dbase + j) * kL + l0 + scol];
                s += qv[j] * qv[j];
            }
            sPsq[(tid >> 6) * 64 + scol] = s;
            f16x8 hq;
#pragma unroll
            for (int j = 0; j < 8; ++j) hq[j] = (f16)qv[j];
            *(f16x8*)&sQt[scol * 64 + (dbase ^ ((scol & 7) << 3))] = hq;
        }
        __syncthreads();

        float sqv = 0.f;
#pragma unroll
        for (int g = 0; g < 8; ++g) sqv += sPsq[g * 64 + lane];
        float sqs[4];
#pragma unroll
        for (int lf = 0; lf < 4; ++lf) sqs[lf] = __shfl(sqv, lf * 16 + l15, 64);

        f32x4 z[2][4];
#pragma unroll
        for (int ri = 0; ri < 2; ++ri)
#pragma unroll
            for (int lf = 0; lf < 4; ++lf) { f32x4 z0 = {0.f, 0.f, 0.f, 0.f}; z[ri][lf] = z0; }

#pragma unroll
        for (int ks = 0; ks < 2; ++ks) {
            f16x8 bfr[4];
#pragma unroll
            for (int lf = 0; lf < 4; ++lf) {
                const int row = 16 * lf + l15;
                bfr[lf] = *(const f16x8*)&sQt[row * 64 + ((32 * ks + 8 * lhi) ^ ((row & 7) << 3))];
            }
#pragma unroll
            for (int ri = 0; ri < 2; ++ri)
#pragma unroll
                for (int lf = 0; lf < 4; ++lf)
                    z[ri][lf] = __builtin_amdgcn_mfma_f32_16x16x32_f16(wfrag[ri][ks], bfr[lf], z[ri][lf], 0, 0, 0);
        }

        // phi -> sPhiT [l][r]; C-frag's 4 consecutive r pack into one b64 store
#pragma unroll
        for (int ri = 0; ri < 2; ++ri) {
            const int r0q = 32 * w + 16 * ri + 4 * lhi;
#pragma unroll
            for (int lf = 0; lf < 4; ++lf) {
                const int lc = 16 * lf + l15;
                f16x4 ph;
#pragma unroll
                for (int j = 0; j < 4; ++j)
                    ph[j] = (f16)(kDnS * __expf(kA + kB * z[ri][lf][j] - sqs[lf]));
                *(f16x4*)&sPhiT[lc * 256 + (r0q ^ ((lc & 7) << 3))] = ph;
            }
        }
        __syncthreads();

        // out_chunk = phiQ^T @ kv   (wave: 16 l rows, 32 dv cols, K = 256 r)
        f32x4 acc2[2];
        { f32x4 z0 = {0.f, 0.f, 0.f, 0.f}; acc2[0] = z0; acc2[1] = z0; }
        const int lrow = 16 * lfo + l15;
#pragma unroll
        for (int ks = 0; ks < 8; ++ks) {
            f16x8 af = *(const f16x8*)&sPhiT[lrow * 256 + ((32 * ks + 8 * lhi) ^ ((lrow & 7) << 3))];
#pragma unroll
            for (int di = 0; di < 2; ++di) {
                const int dv = 32 * dvh + 16 * di + l15;
                f16x8 bf = *(const f16x8*)&kvt[dv * kR + 32 * ks + 8 * lhi];
                acc2[di] = __builtin_amdgcn_mfma_f32_16x16x32_f16(af, bf, acc2[di], 0, 0, 0);
            }
        }
#pragma unroll
        for (int di = 0; di < 2; ++di)
#pragma unroll
            for (int j = 0; j < 4; ++j) {
                const int ll = 16 * lfo + 4 * lhi + j;
                const int dv = 32 * dvh + 16 * di + l15;
                outg[(l0 + ll) * kDV + dv] = acc2[di][j] * kOutScale;
            }
        __syncthreads();
    }
}

extern "C" void kernel_launch(void* const* d_in, const int* in_sizes, int n_in,
                              void* d_out, int out_size, void* d_ws, size_t ws_size,
                              hipStream_t stream)
{
    const float* Q = (const float*)d_in[0];
    const float* K = (const float*)d_in[1];
    const float* V = (const float*)d_in[2];
    const float* W = (const float*)d_in[3];
    float* out = (float*)d_out;
    float* partials = (float*)d_out;  // reuse d_out: 256*16384 f32 == out_size
    f16* kvt = (f16*)d_ws;            // 32 KiB of workspace

    favor_kv_kernel<<<256, 512, 0, stream>>>(K, V, W, partials);
    favor_reduce_kernel<<<256, 256, 0, stream>>>(partials, kvt);
    favor_out_kernel2<<<256, 512, 0, stream>>>(Q, kvt ? W : W, kvt, out);
    // (favor_out_kernel is an unused stub kept only to satisfy earlier definition)
    (void)in_sizes; (void)n_in; (void)out_size; (void)ws_size; (void)Q;
}